// Round 6
// baseline (1309.446 us; speedup 1.0000x reference)
//
#include <hip/hip_runtime.h>
#include <hip/hip_bf16.h>

#define N_NODES 100000
#define N_EDGES 3200000
#define IN_DIM  128
#define HID     32
#define NCLUS   30

// edge_index accessor: f=0 -> int32 layout, f=1 -> int64 layout (read low word)
__device__ __forceinline__ int edge_at(const int* ei, int row, int e, int f) {
  int v = ei[(row * N_EDGES + e) << f];
  return min(max(v, 0), N_NODES - 1);   // defensive clamp
}

// ---- detect int32 vs int64 edge_index ----
__global__ void k_detect(const unsigned int* ei, int* flag) {
  if (threadIdx.x == 0) {
    int zeros = 0;
    for (int i = 1; i < 128; i += 2) zeros += (ei[i] == 0u) ? 1 : 0;
    *flag = (zeros >= 48) ? 1 : 0;   // int64: odd words are (zero) high halves
  }
}

// ---- zero init ----
__global__ void k_zero(int* cnt, float* colsum, float* msef) {
  int t = blockIdx.x * blockDim.x + threadIdx.x;
  if (t < N_NODES) cnt[t] = 0;
  if (t < 32) colsum[t] = 0.0f;
  if (t == 0) *msef = 0.0f;
}

// ---- in-degree count ----
__global__ void k_count(const int* ei, const int* flag, int* cnt) {
  int e = blockIdx.x * blockDim.x + threadIdx.x;
  if (e >= N_EDGES) return;
  int f = *flag;
  atomicAdd(&cnt[edge_at(ei, 1, e, f)], 1);
}

// ---- dinv[n] = rsqrt(in_deg + 1) ----
__global__ void k_dinv(const int* cnt, float* dinv) {
  int t = blockIdx.x * blockDim.x + threadIdx.x;
  if (t < N_NODES) dinv[t] = rsqrtf((float)(cnt[t] + 1));
}

// ---- GEMM1 (fp32): XW[n*32+j] = sum_k x[n,k] * W1[k,j] ----
__global__ void __launch_bounds__(256) k_gemm1f(const float* x, const float* W1, float* XW) {
  __shared__ float Ws[IN_DIM * HID];   // 16 KB
  int tid = threadIdx.x;
  for (int i = tid; i < IN_DIM * HID; i += 256) Ws[i] = W1[i];
  __syncthreads();
  int j = tid & 31, r = tid >> 5;
  int n = blockIdx.x * 8 + r;
  if (n >= N_NODES) return;
  const float* xr = x + (size_t)n * IN_DIM;
  float acc = 0.0f;
  #pragma unroll
  for (int k = 0; k < IN_DIM; k++) acc += xr[k] * Ws[k * HID + j];
  XW[n * 32 + j] = acc;
}

// ---- edge aggregation: D[d,j] += S[s,j] * dinv[s] * dinv[d]  (j = 0..31) ----
__global__ void __launch_bounds__(256) k_eaggf(const int* ei, const int* flag, const float* dinv,
                                               const float* S, float* D) {
  int j = threadIdx.x & 31, g = threadIdx.x >> 5;
  int f = *flag;
  for (int e = blockIdx.x * 8 + g; e < N_EDGES; e += gridDim.x * 8) {
    int s = edge_at(ei, 0, e, f);
    int d = edge_at(ei, 1, e, f);
    float w = dinv[s] * dinv[d];
    atomicAdd(&D[d * 32 + j], S[s * 32 + j] * w);
  }
}

// ---- layer1 finish: h = relu(edge_sums + self_loop + b1), in place into XW ----
__global__ void k_reluf(const float* A, const float* dinv, const float* b1, float* XW) {
  int t = blockIdx.x * blockDim.x + threadIdx.x;
  if (t >= N_NODES * 32) return;
  int n = t >> 5, j = t & 31;
  float di = dinv[n];
  float v = A[t] + XW[t] * di * di + b1[j];
  XW[t] = fmaxf(v, 0.0f);
}

// ---- GEMM2 (fp32): G[n*32+j] = sum_k h[n,k] * W2[k,j] (j<30; cols 30,31 zeroed) ----
__global__ void __launch_bounds__(256) k_gemm2f(const float* h, const float* W2, float* G) {
  __shared__ float Ws[HID * 32];
  int tid = threadIdx.x;
  for (int i = tid; i < HID * 32; i += 256) Ws[i] = 0.0f;
  __syncthreads();
  for (int i = tid; i < HID * NCLUS; i += 256) {
    int k = i / NCLUS, j = i % NCLUS;
    Ws[k * 32 + j] = W2[i];
  }
  __syncthreads();
  int j = tid & 31, r = tid >> 5;
  int n = blockIdx.x * 8 + r;
  if (n >= N_NODES) return;
  const float* hr = h + (size_t)n * 32;
  float acc = 0.0f;
  #pragma unroll
  for (int k = 0; k < HID; k++) acc += hr[k] * Ws[k * 32 + j];
  G[n * 32 + j] = (j < NCLUS) ? acc : 0.0f;
}

// ---- layer2 finish + serial softmax; FX -> out (fp32, stride 30) ----
__global__ void __launch_bounds__(256) k_softmaxf(const float* G, const float* AG, const float* dinv,
                                                  const float* b2, float* outp) {
  int n = blockIdx.x * blockDim.x + threadIdx.x;
  if (n >= N_NODES) return;
  float di = dinv[n], di2 = di * di;
  float lg[NCLUS];
  float m = -1e30f;
  #pragma unroll
  for (int j = 0; j < NCLUS; j++) {
    float v = AG[n * 32 + j] + G[n * 32 + j] * di2 + b2[j];
    v = fminf(fmaxf(v, -80.0f), 80.0f);   // safety net (inactive for sane logits)
    lg[j] = v; m = fmaxf(m, v);
  }
  float ssum = 0.0f;
  #pragma unroll
  for (int j = 0; j < NCLUS; j++) { lg[j] = __expf(lg[j] - m); ssum += lg[j]; }
  float inv = 1.0f / ssum;
  #pragma unroll
  for (int j = 0; j < NCLUS; j++) outp[n * NCLUS + j] = lg[j] * inv;
}

// ---- edge MSE (fp32 FX from out, stride 30) ----
__global__ void __launch_bounds__(256) k_msef(const int* ei, const float* ep,
                                              const float* FX, const int* flag, float* msef) {
  __shared__ float sd[256];
  int tid = threadIdx.x;
  int j = tid & 31, g = tid >> 5;
  int f = *flag;
  float local = 0.0f;
  for (int e = blockIdx.x * 8 + g; e < N_EDGES; e += gridDim.x * 8) {
    int s = edge_at(ei, 0, e, f);
    int d = edge_at(ei, 1, e, f);
    float v = (j < NCLUS) ? FX[s * NCLUS + j] * FX[d * NCLUS + j] : 0.0f;
    #pragma unroll
    for (int mask = 16; mask > 0; mask >>= 1) v += __shfl_xor(v, mask, 32);
    if (j == 0) { float diff = v - ep[e]; local += diff * diff; }
  }
  sd[tid] = local; __syncthreads();
  for (int off = 128; off > 0; off >>= 1) {
    if (tid < off) sd[tid] += sd[tid + off];
    __syncthreads();
  }
  if (tid == 0) atomicAdd(msef, sd[0]);
}

// ---- column sums of log(1-FX^2) (fp32 FX from out, stride 30) ----
__global__ void __launch_bounds__(256) k_colsumf(const float* FX, float* colsum) {
  __shared__ float sd[256];
  int tid = threadIdx.x;
  int j = tid & 31, g = tid >> 5;
  float local = 0.0f;
  if (j < NCLUS) {
    for (int n = blockIdx.x * 8 + g; n < N_NODES; n += gridDim.x * 8) {
      float v = FX[n * NCLUS + j];
      local += log1pf(-v * v);
    }
  }
  sd[tid] = local; __syncthreads();
  if (tid < 32) {
    float s = 0.0f;
    #pragma unroll
    for (int gg = 0; gg < 8; gg++) s += sd[tid + 32 * gg];
    if (tid < NCLUS) atomicAdd(&colsum[tid], s);
  }
}

// ---- final loss (fp32) ----
__global__ void k_final(const float* colsum, const float* msef, float* out) {
  int tid = threadIdx.x;
  float v = 0.0f;
  if (tid < NCLUS) v = logf(1.0001f - __expf(colsum[tid]));
  #pragma unroll
  for (int mask = 32; mask > 0; mask >>= 1) v += __shfl_xor(v, mask, 64);
  if (tid == 0) {
    float preg = -v;
    float msev = *msef / (float)N_EDGES;
    out[(size_t)N_NODES * NCLUS] = msev + 0.01f * preg;
  }
}

extern "C" void kernel_launch(void* const* d_in, const int* in_sizes, int n_in,
                              void* d_out, int out_size, void* d_ws, size_t ws_size,
                              hipStream_t stream) {
  const float* x  = (const float*)d_in[0];
  const int*   ei = (const int*)d_in[1];
  const float* ep = (const float*)d_in[2];
  const float* W1 = (const float*)d_in[3];
  const float* b1 = (const float*)d_in[4];
  const float* W2 = (const float*)d_in[5];
  const float* b2 = (const float*)d_in[6];
  float* out = (float*)d_out;   // fp32 output: FX[100000*30] then loss scalar

  char* ws = (char*)d_ws;
  size_t off = 0;
  auto alloc = [&](size_t bytes) { size_t o = off; off += (bytes + 255) & ~(size_t)255; return o; };

  size_t o_hdr  = alloc(1024);                       // flag@0, msef@8, colsum@256
  size_t o_cnt  = alloc((size_t)N_NODES * 4);        // 400 KB
  size_t o_dinv = alloc((size_t)N_NODES * 4);        // 400 KB
  size_t o_XW   = alloc((size_t)N_NODES * 32 * 4);   // 12.8 MB: x@W1 -> h -> agg2 sums
  size_t o_A    = alloc((size_t)N_NODES * 32 * 4);   // 12.8 MB: agg1 sums -> G2
  (void)ws_size;                                     // total ~26.4 MB

  int*   flag   = (int*)(ws + o_hdr);
  float* msef   = (float*)(ws + o_hdr + 8);
  float* colsum = (float*)(ws + o_hdr + 256);
  int*   cnt    = (int*)(ws + o_cnt);
  float* dinv   = (float*)(ws + o_dinv);
  float* XW     = (float*)(ws + o_XW);
  float* A      = (float*)(ws + o_A);

  const int nodeBlocks = (N_NODES + 255) / 256;          // 391
  const int edgeBlocks = (N_EDGES + 255) / 256;          // 12500
  const int grpBlocks  = (N_NODES + 7) / 8;              // 12500
  const int elemBlocks = (N_NODES * 32 + 255) / 256;     // 12500

  k_detect<<<1, 64, 0, stream>>>((const unsigned int*)ei, flag);
  k_zero<<<nodeBlocks, 256, 0, stream>>>(cnt, colsum, msef);
  k_count<<<edgeBlocks, 256, 0, stream>>>(ei, flag, cnt);
  k_dinv<<<nodeBlocks, 256, 0, stream>>>(cnt, dinv);

  // layer 1: XW = x@W1 ; A = edge sums ; XW <- h = relu(A + selfloop + b1)
  k_gemm1f<<<grpBlocks, 256, 0, stream>>>(x, W1, XW);
  hipMemsetAsync(A, 0, (size_t)N_NODES * 32 * 4, stream);
  k_eaggf<<<8192, 256, 0, stream>>>(ei, flag, dinv, XW, A);
  k_reluf<<<elemBlocks, 256, 0, stream>>>(A, dinv, b1, XW);

  // layer 2: A = h@W2 (G2) ; XW = edge sums ; softmax -> out (fp32 FX)
  k_gemm2f<<<grpBlocks, 256, 0, stream>>>(XW, W2, A);
  hipMemsetAsync(XW, 0, (size_t)N_NODES * 32 * 4, stream);
  k_eaggf<<<8192, 256, 0, stream>>>(ei, flag, dinv, A, XW);
  k_softmaxf<<<nodeBlocks, 256, 0, stream>>>(A, XW, dinv, b2, out);

  // loss (reads FX from out, stride 30)
  k_msef<<<4096, 256, 0, stream>>>(ei, ep, out, flag, msef);
  k_colsumf<<<256, 256, 0, stream>>>(out, colsum);
  k_final<<<1, 64, 0, stream>>>(colsum, msef, out);
}

// Round 7
// 1056.863 us; speedup vs baseline: 1.2390x; 1.2390x over previous
//
#include <hip/hip_runtime.h>
#include <hip/hip_bf16.h>

#define N_NODES 100000
#define N_EDGES 3200000
#define IN_DIM  128
#define HID     32
#define NCLUS   30
#define SCAN_CHUNK 1024
#define SCAN_NBLK  98   // ceil(100000/1024)

// edge_index accessor: f=0 -> int32 layout, f=1 -> int64 layout (read low word)
__device__ __forceinline__ int edge_at(const int* ei, int row, int e, int f) {
  int v = ei[(row * N_EDGES + e) << f];
  return min(max(v, 0), N_NODES - 1);   // defensive clamp
}

// ---- detect int32 vs int64 edge_index ----
__global__ void k_detect(const unsigned int* ei, int* flag) {
  if (threadIdx.x == 0) {
    int zeros = 0;
    for (int i = 1; i < 128; i += 2) zeros += (ei[i] == 0u) ? 1 : 0;
    *flag = (zeros >= 48) ? 1 : 0;
  }
}

// ---- zero init ----
__global__ void k_zero(int* cnt, float* colsum, float* msef) {
  int t = blockIdx.x * blockDim.x + threadIdx.x;
  if (t < N_NODES) cnt[t] = 0;
  if (t < 32) colsum[t] = 0.0f;
  if (t == 0) *msef = 0.0f;
}

// ---- in-degree count ----
__global__ void k_count(const int* ei, const int* flag, int* cnt) {
  int e = blockIdx.x * blockDim.x + threadIdx.x;
  if (e >= N_EDGES) return;
  int f = *flag;
  atomicAdd(&cnt[edge_at(ei, 1, e, f)], 1);
}

// ---- dinv[n] = rsqrt(in_deg + 1) ----
__global__ void k_dinv(const int* cnt, float* dinv) {
  int t = blockIdx.x * blockDim.x + threadIdx.x;
  if (t < N_NODES) dinv[t] = rsqrtf((float)(cnt[t] + 1));
}

// ---- scan stage 1: per-1024-chunk totals ----
__global__ void k_scan1(const int* cnt, int* bsum) {
  __shared__ int sd[256];
  int tid = threadIdx.x;
  int base = blockIdx.x * SCAN_CHUNK;
  int s = 0;
  for (int i = tid; i < SCAN_CHUNK; i += 256) {
    int idx = base + i;
    s += (idx < N_NODES) ? cnt[idx] : 0;
  }
  sd[tid] = s; __syncthreads();
  for (int off = 128; off > 0; off >>= 1) {
    if (tid < off) sd[tid] += sd[tid + off];
    __syncthreads();
  }
  if (tid == 0) bsum[blockIdx.x] = sd[0];
}

// ---- scan stage 2 ----
__global__ void k_scan2(int* bsum) {
  if (threadIdx.x == 0) {
    int run = 0;
    for (int i = 0; i < SCAN_NBLK; i++) { int t = bsum[i]; bsum[i] = run; run += t; }
  }
}

// ---- scan stage 3: cursor = exclusive prefix of cnt ----
__global__ void k_scan3(const int* cnt, const int* bsum, int* cursor) {
  __shared__ int ts[256];
  int tid = threadIdx.x;
  int base = blockIdx.x * SCAN_CHUNK + tid * 4;
  int v[4]; int s = 0;
  #pragma unroll
  for (int j = 0; j < 4; j++) {
    int idx = base + j;
    v[j] = (idx < N_NODES) ? cnt[idx] : 0;
    s += v[j];
  }
  ts[tid] = s; __syncthreads();
  for (int off = 1; off < 256; off <<= 1) {
    int t = (tid >= off) ? ts[tid - off] : 0;
    __syncthreads();
    ts[tid] += t;
    __syncthreads();
  }
  int excl = bsum[blockIdx.x] + (tid > 0 ? ts[tid - 1] : 0);
  #pragma unroll
  for (int j = 0; j < 4; j++) {
    int idx = base + j;
    if (idx < N_NODES) { cursor[idx] = excl; excl += v[j]; }
  }
}

// ---- CSR scatter (after this, cursor[n] == row end) ----
__global__ void k_scatter(const int* ei, const int* flag, int* cursor, int* csr_src) {
  int e = blockIdx.x * blockDim.x + threadIdx.x;
  if (e >= N_EDGES) return;
  int f = *flag;
  int s = edge_at(ei, 0, e, f);
  int d = edge_at(ei, 1, e, f);
  int pos = atomicAdd(&cursor[d], 1);
  csr_src[pos] = s;
}

// ---- GEMM1 scaled: G1[n*32+j] = (sum_k x[n,k]*W1[k,j]) * dinv[n] ----
__global__ void __launch_bounds__(256) k_gemm1s(const float* x, const float* W1,
                                                const float* dinv, float* G1) {
  __shared__ float Ws[IN_DIM * HID];   // 16 KB
  int tid = threadIdx.x;
  for (int i = tid; i < IN_DIM * HID; i += 256) Ws[i] = W1[i];
  __syncthreads();
  int j = tid & 31, r = tid >> 5;
  int n = blockIdx.x * 8 + r;
  if (n >= N_NODES) return;
  const float* xr = x + (size_t)n * IN_DIM;
  float acc = 0.0f;
  #pragma unroll
  for (int k = 0; k < IN_DIM; k++) acc += xr[k] * Ws[k * HID + j];
  G1[n * 32 + j] = acc * dinv[n];
}

// ---- GEMM2 scaled: G2[n*32+j] = (sum_k h[n,k]*W2[k,j]) * dinv[n]; cols 30,31 = 0 ----
__global__ void __launch_bounds__(256) k_gemm2s(const float* h, const float* W2,
                                                const float* dinv, float* G2) {
  __shared__ float Ws[HID * 32];
  int tid = threadIdx.x;
  for (int i = tid; i < HID * 32; i += 256) Ws[i] = 0.0f;
  __syncthreads();
  for (int i = tid; i < HID * NCLUS; i += 256) {
    int k = i / NCLUS, j = i % NCLUS;
    Ws[k * 32 + j] = W2[i];
  }
  __syncthreads();
  int j = tid & 31, r = tid >> 5;
  int n = blockIdx.x * 8 + r;
  if (n >= N_NODES) return;
  const float* hr = h + (size_t)n * 32;
  float acc = 0.0f;
  #pragma unroll
  for (int k = 0; k < HID; k++) acc += hr[k] * Ws[k * 32 + j];
  G2[n * 32 + j] = (j < NCLUS) ? acc * dinv[n] : 0.0f;
}

// ---- CSR agg layer1: h[n] = relu(dinv[n]*(G1[n] + sum_csr G1[s]) + b1) ----
__global__ void __launch_bounds__(256) k_agg1g(const float* G, const int* cursor, const int* cnt,
                                               const int* csr, const float* dinv,
                                               const float* b1, float* h) {
  int j = threadIdx.x & 31, g = threadIdx.x >> 5;
  int n = blockIdx.x * 8 + g;
  if (n >= N_NODES) return;
  int len = cnt[n];
  int st = cursor[n] - len;
  float acc = G[n * 32 + j];
  int i = 0;
  for (; i + 4 <= len; i += 4) {
    int s0 = csr[st + i], s1 = csr[st + i + 1], s2 = csr[st + i + 2], s3 = csr[st + i + 3];
    float v0 = G[s0 * 32 + j], v1 = G[s1 * 32 + j], v2 = G[s2 * 32 + j], v3 = G[s3 * 32 + j];
    acc += (v0 + v1) + (v2 + v3);
  }
  for (; i < len; i++) acc += G[csr[st + i] * 32 + j];
  h[n * 32 + j] = fmaxf(dinv[n] * acc + b1[j], 0.0f);
}

// ---- CSR agg layer2 + softmax -> out (fp32, stride 30) ----
__global__ void __launch_bounds__(256) k_agg2g(const float* G, const int* cursor, const int* cnt,
                                               const int* csr, const float* dinv,
                                               const float* b2, float* outp) {
  int j = threadIdx.x & 31, g = threadIdx.x >> 5;
  int n = blockIdx.x * 8 + g;
  if (n >= N_NODES) return;
  int len = cnt[n];
  int st = cursor[n] - len;
  float acc = G[n * 32 + j];
  int i = 0;
  for (; i + 4 <= len; i += 4) {
    int s0 = csr[st + i], s1 = csr[st + i + 1], s2 = csr[st + i + 2], s3 = csr[st + i + 3];
    float v0 = G[s0 * 32 + j], v1 = G[s1 * 32 + j], v2 = G[s2 * 32 + j], v3 = G[s3 * 32 + j];
    acc += (v0 + v1) + (v2 + v3);
  }
  for (; i < len; i++) acc += G[csr[st + i] * 32 + j];
  bool act = (j < NCLUS);
  float logit = act ? fminf(fmaxf(dinv[n] * acc + b2[j], -80.0f), 80.0f) : -1e30f;
  float m = logit;
  #pragma unroll
  for (int mask = 16; mask > 0; mask >>= 1) m = fmaxf(m, __shfl_xor(m, mask, 32));
  float ex = act ? __expf(logit - m) : 0.0f;
  float ssum = ex;
  #pragma unroll
  for (int mask = 16; mask > 0; mask >>= 1) ssum += __shfl_xor(ssum, mask, 32);
  if (act) outp[n * NCLUS + j] = ex / fmaxf(ssum, 1e-30f);
}

// ---- atomic fallback: D[d,j] += G[s,j] (G pre-scaled by dinv[s]) ----
__global__ void __launch_bounds__(256) k_eagg2(const int* ei, const int* flag,
                                               const float* G, float* D) {
  int j = threadIdx.x & 31, g = threadIdx.x >> 5;
  int f = *flag;
  for (int e = blockIdx.x * 8 + g; e < N_EDGES; e += gridDim.x * 8) {
    int s = edge_at(ei, 0, e, f);
    int d = edge_at(ei, 1, e, f);
    atomicAdd(&D[d * 32 + j], G[s * 32 + j]);
  }
}

// ---- atomic fallback: h = relu(dinv*(A + G1) + b1), in place into G1 ----
__global__ void k_relu2(const float* A, const float* dinv, const float* b1, float* G) {
  int t = blockIdx.x * blockDim.x + threadIdx.x;
  if (t >= N_NODES * 32) return;
  int n = t >> 5, j = t & 31;
  G[t] = fmaxf(dinv[n] * (A[t] + G[t]) + b1[j], 0.0f);
}

// ---- atomic fallback: softmax(dinv*(S + G2) + b2) -> out ----
__global__ void __launch_bounds__(256) k_softmax2(const float* S, const float* G2, const float* dinv,
                                                  const float* b2, float* outp) {
  int n = blockIdx.x * blockDim.x + threadIdx.x;
  if (n >= N_NODES) return;
  float di = dinv[n];
  float lg[NCLUS];
  float m = -1e30f;
  #pragma unroll
  for (int j = 0; j < NCLUS; j++) {
    float v = di * (S[n * 32 + j] + G2[n * 32 + j]) + b2[j];
    v = fminf(fmaxf(v, -80.0f), 80.0f);
    lg[j] = v; m = fmaxf(m, v);
  }
  float ssum = 0.0f;
  #pragma unroll
  for (int j = 0; j < NCLUS; j++) { lg[j] = __expf(lg[j] - m); ssum += lg[j]; }
  float inv = 1.0f / ssum;
  #pragma unroll
  for (int j = 0; j < NCLUS; j++) outp[n * NCLUS + j] = lg[j] * inv;
}

// ---- edge MSE (fp32 FX from out, stride 30) ----
__global__ void __launch_bounds__(256) k_msef(const int* ei, const float* ep,
                                              const float* FX, const int* flag, float* msef) {
  __shared__ float sd[256];
  int tid = threadIdx.x;
  int j = tid & 31, g = tid >> 5;
  int f = *flag;
  float local = 0.0f;
  for (int e = blockIdx.x * 8 + g; e < N_EDGES; e += gridDim.x * 8) {
    int s = edge_at(ei, 0, e, f);
    int d = edge_at(ei, 1, e, f);
    float v = (j < NCLUS) ? FX[s * NCLUS + j] * FX[d * NCLUS + j] : 0.0f;
    #pragma unroll
    for (int mask = 16; mask > 0; mask >>= 1) v += __shfl_xor(v, mask, 32);
    if (j == 0) { float diff = v - ep[e]; local += diff * diff; }
  }
  sd[tid] = local; __syncthreads();
  for (int off = 128; off > 0; off >>= 1) {
    if (tid < off) sd[tid] += sd[tid + off];
    __syncthreads();
  }
  if (tid == 0) atomicAdd(msef, sd[0]);
}

// ---- column sums of log(1-FX^2) ----
__global__ void __launch_bounds__(256) k_colsumf(const float* FX, float* colsum) {
  __shared__ float sd[256];
  int tid = threadIdx.x;
  int j = tid & 31, g = tid >> 5;
  float local = 0.0f;
  if (j < NCLUS) {
    for (int n = blockIdx.x * 8 + g; n < N_NODES; n += gridDim.x * 8) {
      float v = FX[n * NCLUS + j];
      local += log1pf(-v * v);
    }
  }
  sd[tid] = local; __syncthreads();
  if (tid < 32) {
    float s = 0.0f;
    #pragma unroll
    for (int gg = 0; gg < 8; gg++) s += sd[tid + 32 * gg];
    if (tid < NCLUS) atomicAdd(&colsum[tid], s);
  }
}

// ---- final loss (fp32) ----
__global__ void k_final(const float* colsum, const float* msef, float* out) {
  int tid = threadIdx.x;
  float v = 0.0f;
  if (tid < NCLUS) v = logf(1.0001f - __expf(colsum[tid]));
  #pragma unroll
  for (int mask = 32; mask > 0; mask >>= 1) v += __shfl_xor(v, mask, 64);
  if (tid == 0) {
    float preg = -v;
    float msev = *msef / (float)N_EDGES;
    out[(size_t)N_NODES * NCLUS] = msev + 0.01f * preg;
  }
}

extern "C" void kernel_launch(void* const* d_in, const int* in_sizes, int n_in,
                              void* d_out, int out_size, void* d_ws, size_t ws_size,
                              hipStream_t stream) {
  const float* x  = (const float*)d_in[0];
  const int*   ei = (const int*)d_in[1];
  const float* ep = (const float*)d_in[2];
  const float* W1 = (const float*)d_in[3];
  const float* b1 = (const float*)d_in[4];
  const float* W2 = (const float*)d_in[5];
  const float* b2 = (const float*)d_in[6];
  float* out = (float*)d_out;   // fp32: FX[100000*30] then loss scalar

  char* ws = (char*)d_ws;
  size_t off = 0;
  auto alloc = [&](size_t bytes) { size_t o = off; off += (bytes + 255) & ~(size_t)255; return o; };

  size_t o_hdr  = alloc(1024);                       // flag@0, msef@8, colsum@256, bsum@512
  size_t o_cnt  = alloc((size_t)N_NODES * 4);
  size_t o_dinv = alloc((size_t)N_NODES * 4);
  size_t o_B1   = alloc((size_t)N_NODES * 32 * 4);   // G1 -> (fallback: h in place)
  size_t o_B2   = alloc((size_t)N_NODES * 32 * 4);   // h / sums / G2

  int*   flag   = (int*)(ws + o_hdr);
  float* msef   = (float*)(ws + o_hdr + 8);
  float* colsum = (float*)(ws + o_hdr + 256);
  int*   bsum   = (int*)(ws + o_hdr + 512);
  int*   cnt    = (int*)(ws + o_cnt);
  float* dinv   = (float*)(ws + o_dinv);
  float* B1     = (float*)(ws + o_B1);
  float* B2     = (float*)(ws + o_B2);

  const int nodeBlocks = (N_NODES + 255) / 256;          // 391
  const int edgeBlocks = (N_EDGES + 255) / 256;          // 12500
  const int grpBlocks  = (N_NODES + 7) / 8;              // 12500
  const int elemBlocks = (N_NODES * 32 + 255) / 256;     // 12500

  k_detect<<<1, 64, 0, stream>>>((const unsigned int*)ei, flag);
  k_zero<<<nodeBlocks, 256, 0, stream>>>(cnt, colsum, msef);
  k_count<<<edgeBlocks, 256, 0, stream>>>(ei, flag, cnt);
  k_dinv<<<nodeBlocks, 256, 0, stream>>>(cnt, dinv);

  // CSR path needs cursor (0.4 MB) + csr (12.8 MB) on top of the common ~27 MB
  size_t o_cursor = alloc((size_t)N_NODES * 4);
  size_t o_csr    = alloc((size_t)N_EDGES * 4);
  bool use_csr = (off <= ws_size);

  if (use_csr) {
    int* cursor = (int*)(ws + o_cursor);
    int* csr    = (int*)(ws + o_csr);
    k_scan1<<<SCAN_NBLK, 256, 0, stream>>>(cnt, bsum);
    k_scan2<<<1, 64, 0, stream>>>(bsum);
    k_scan3<<<SCAN_NBLK, 256, 0, stream>>>(cnt, bsum, cursor);
    k_scatter<<<edgeBlocks, 256, 0, stream>>>(ei, flag, cursor, csr);

    k_gemm1s<<<grpBlocks, 256, 0, stream>>>(x, W1, dinv, B1);            // B1 = G1
    k_agg1g<<<grpBlocks, 256, 0, stream>>>(B1, cursor, cnt, csr, dinv, b1, B2);  // B2 = h
    k_gemm2s<<<grpBlocks, 256, 0, stream>>>(B2, W2, dinv, B1);           // B1 = G2
    k_agg2g<<<grpBlocks, 256, 0, stream>>>(B1, cursor, cnt, csr, dinv, b2, out); // FX
  } else {
    // atomic fallback (proven in R6), scaled-G variant
    k_gemm1s<<<grpBlocks, 256, 0, stream>>>(x, W1, dinv, B1);            // B1 = G1
    hipMemsetAsync(B2, 0, (size_t)N_NODES * 32 * 4, stream);
    k_eagg2<<<8192, 256, 0, stream>>>(ei, flag, B1, B2);                 // B2 = sums
    k_relu2<<<elemBlocks, 256, 0, stream>>>(B2, dinv, b1, B1);           // B1 = h
    k_gemm2s<<<grpBlocks, 256, 0, stream>>>(B1, W2, dinv, B2);           // B2 = G2
    hipMemsetAsync(B1, 0, (size_t)N_NODES * 32 * 4, stream);
    k_eagg2<<<8192, 256, 0, stream>>>(ei, flag, B2, B1);                 // B1 = sums
    k_softmax2<<<nodeBlocks, 256, 0, stream>>>(B1, B2, dinv, b2, out);   // FX
  }

  // loss (reads FX from out, stride 30)
  k_msef<<<4096, 256, 0, stream>>>(ei, ep, out, flag, msef);
  k_colsumf<<<256, 256, 0, stream>>>(out, colsum);
  k_final<<<1, 64, 0, stream>>>(colsum, msef, out);
}

// Round 8
// 1033.080 us; speedup vs baseline: 1.2675x; 1.0230x over previous
//
#include <hip/hip_runtime.h>
#include <hip/hip_bf16.h>

#define N_NODES 100000
#define N_EDGES 3200000
#define IN_DIM  128
#define HID     32
#define NCLUS   30
#define SCAN_CHUNK 1024
#define SCAN_NBLK  98   // ceil(100000/1024)

__device__ __forceinline__ float bf2f(__hip_bfloat16 v) { return __bfloat162float(v); }

// edge_index accessor: f=0 -> int32 layout, f=1 -> int64 layout (read low word)
__device__ __forceinline__ int edge_at(const int* ei, int row, int e, int f) {
  int v = ei[(row * N_EDGES + e) << f];
  return min(max(v, 0), N_NODES - 1);
}

// ---- detect int32 vs int64 edge_index ----
__global__ void k_detect(const unsigned int* ei, int* flag) {
  if (threadIdx.x == 0) {
    int zeros = 0;
    for (int i = 1; i < 128; i += 2) zeros += (ei[i] == 0u) ? 1 : 0;
    *flag = (zeros >= 48) ? 1 : 0;
  }
}

// ---- zero init ----
__global__ void k_zero(int* cnt, float* colsum, double* msed) {
  int t = blockIdx.x * blockDim.x + threadIdx.x;
  if (t < N_NODES) cnt[t] = 0;
  if (t < 32) colsum[t] = 0.0f;
  if (t == 0) *msed = 0.0;
}

// ---- in-degree count ----
__global__ void k_count(const int* ei, const int* flag, int* cnt) {
  int e = blockIdx.x * blockDim.x + threadIdx.x;
  if (e >= N_EDGES) return;
  int f = *flag;
  atomicAdd(&cnt[edge_at(ei, 1, e, f)], 1);
}

// ---- dinv[n] = rsqrt(in_deg + 1) ----
__global__ void k_dinv(const int* cnt, float* dinv) {
  int t = blockIdx.x * blockDim.x + threadIdx.x;
  if (t < N_NODES) dinv[t] = rsqrtf((float)(cnt[t] + 1));
}

// ---- scan stage 1 ----
__global__ void k_scan1(const int* cnt, int* bsum) {
  __shared__ int sd[256];
  int tid = threadIdx.x;
  int base = blockIdx.x * SCAN_CHUNK;
  int s = 0;
  for (int i = tid; i < SCAN_CHUNK; i += 256) {
    int idx = base + i;
    s += (idx < N_NODES) ? cnt[idx] : 0;
  }
  sd[tid] = s; __syncthreads();
  for (int off = 128; off > 0; off >>= 1) {
    if (tid < off) sd[tid] += sd[tid + off];
    __syncthreads();
  }
  if (tid == 0) bsum[blockIdx.x] = sd[0];
}

// ---- scan stage 2 ----
__global__ void k_scan2(int* bsum) {
  if (threadIdx.x == 0) {
    int run = 0;
    for (int i = 0; i < SCAN_NBLK; i++) { int t = bsum[i]; bsum[i] = run; run += t; }
  }
}

// ---- scan stage 3 ----
__global__ void k_scan3(const int* cnt, const int* bsum, int* cursor) {
  __shared__ int ts[256];
  int tid = threadIdx.x;
  int base = blockIdx.x * SCAN_CHUNK + tid * 4;
  int v[4]; int s = 0;
  #pragma unroll
  for (int j = 0; j < 4; j++) {
    int idx = base + j;
    v[j] = (idx < N_NODES) ? cnt[idx] : 0;
    s += v[j];
  }
  ts[tid] = s; __syncthreads();
  for (int off = 1; off < 256; off <<= 1) {
    int t = (tid >= off) ? ts[tid - off] : 0;
    __syncthreads();
    ts[tid] += t;
    __syncthreads();
  }
  int excl = bsum[blockIdx.x] + (tid > 0 ? ts[tid - 1] : 0);
  #pragma unroll
  for (int j = 0; j < 4; j++) {
    int idx = base + j;
    if (idx < N_NODES) { cursor[idx] = excl; excl += v[j]; }
  }
}

// ---- CSR scatter ----
__global__ void k_scatter(const int* ei, const int* flag, int* cursor, int* csr_src) {
  int e = blockIdx.x * blockDim.x + threadIdx.x;
  if (e >= N_EDGES) return;
  int f = *flag;
  int s = edge_at(ei, 0, e, f);
  int d = edge_at(ei, 1, e, f);
  int pos = atomicAdd(&cursor[d], 1);
  csr_src[pos] = s;
}

// ---- GEMM1 scaled -> bf16: G1[n*32+j] = bf16((x@W1)[n,j] * dinv[n]) ----
__global__ void __launch_bounds__(256) k_gemm1b(const float* x, const float* W1,
                                                const float* dinv, __hip_bfloat16* G1) {
  __shared__ float Ws[IN_DIM * HID];
  int tid = threadIdx.x;
  for (int i = tid; i < IN_DIM * HID; i += 256) Ws[i] = W1[i];
  __syncthreads();
  int j = tid & 31, r = tid >> 5;
  int n = blockIdx.x * 8 + r;
  if (n >= N_NODES) return;
  const float* xr = x + (size_t)n * IN_DIM;
  float acc = 0.0f;
  #pragma unroll
  for (int k = 0; k < IN_DIM; k++) acc += xr[k] * Ws[k * HID + j];
  G1[n * 32 + j] = __float2bfloat16(acc * dinv[n]);
}

// ---- CSR agg layer1 (bf16 gather): h[n] = relu(dinv[n]*(G1[n]+sum G1[s]) + b1), fp32 ----
__global__ void __launch_bounds__(256) k_agg1b(const __hip_bfloat16* G, const int* cursor,
                                               const int* cnt, const int* csr, const float* dinv,
                                               const float* b1, float* h) {
  int j = threadIdx.x & 31, g = threadIdx.x >> 5;
  int n = blockIdx.x * 8 + g;
  if (n >= N_NODES) return;
  int len = cnt[n];
  int st = cursor[n] - len;
  float acc = bf2f(G[n * 32 + j]);
  int i = 0;
  for (; i + 4 <= len; i += 4) {
    int s0 = csr[st + i], s1 = csr[st + i + 1], s2 = csr[st + i + 2], s3 = csr[st + i + 3];
    float v0 = bf2f(G[s0 * 32 + j]), v1 = bf2f(G[s1 * 32 + j]);
    float v2 = bf2f(G[s2 * 32 + j]), v3 = bf2f(G[s3 * 32 + j]);
    acc += (v0 + v1) + (v2 + v3);
  }
  for (; i < len; i++) acc += bf2f(G[csr[st + i] * 32 + j]);
  h[n * 32 + j] = fmaxf(dinv[n] * acc + b1[j], 0.0f);
}

// ---- GEMM2 scaled -> bf16: G2[n*32+j] = bf16((h@W2)[n,j] * dinv[n]); cols 30,31 = 0 ----
__global__ void __launch_bounds__(256) k_gemm2b(const float* h, const float* W2,
                                                const float* dinv, __hip_bfloat16* G2) {
  __shared__ float Ws[HID * 32];
  int tid = threadIdx.x;
  for (int i = tid; i < HID * 32; i += 256) Ws[i] = 0.0f;
  __syncthreads();
  for (int i = tid; i < HID * NCLUS; i += 256) {
    int k = i / NCLUS, j = i % NCLUS;
    Ws[k * 32 + j] = W2[i];
  }
  __syncthreads();
  int j = tid & 31, r = tid >> 5;
  int n = blockIdx.x * 8 + r;
  if (n >= N_NODES) return;
  const float* hr = h + (size_t)n * 32;
  float acc = 0.0f;
  #pragma unroll
  for (int k = 0; k < HID; k++) acc += hr[k] * Ws[k * 32 + j];
  G2[n * 32 + j] = __float2bfloat16((j < NCLUS) ? acc * dinv[n] : 0.0f);
}

// ---- CSR agg layer2 (bf16 gather) + softmax -> out (fp32) + fx16 (bf16, 32-padded) ----
__global__ void __launch_bounds__(256) k_agg2b(const __hip_bfloat16* G, const int* cursor,
                                               const int* cnt, const int* csr, const float* dinv,
                                               const float* b2, float* outp, __hip_bfloat16* fx16) {
  int j = threadIdx.x & 31, g = threadIdx.x >> 5;
  int n = blockIdx.x * 8 + g;
  if (n >= N_NODES) return;
  int len = cnt[n];
  int st = cursor[n] - len;
  float acc = bf2f(G[n * 32 + j]);
  int i = 0;
  for (; i + 4 <= len; i += 4) {
    int s0 = csr[st + i], s1 = csr[st + i + 1], s2 = csr[st + i + 2], s3 = csr[st + i + 3];
    float v0 = bf2f(G[s0 * 32 + j]), v1 = bf2f(G[s1 * 32 + j]);
    float v2 = bf2f(G[s2 * 32 + j]), v3 = bf2f(G[s3 * 32 + j]);
    acc += (v0 + v1) + (v2 + v3);
  }
  for (; i < len; i++) acc += bf2f(G[csr[st + i] * 32 + j]);
  bool act = (j < NCLUS);
  float logit = act ? fminf(fmaxf(dinv[n] * acc + b2[j], -80.0f), 80.0f) : -1e30f;
  float m = logit;
  #pragma unroll
  for (int mask = 16; mask > 0; mask >>= 1) m = fmaxf(m, __shfl_xor(m, mask, 32));
  float ex = act ? __expf(logit - m) : 0.0f;
  float ssum = ex;
  #pragma unroll
  for (int mask = 16; mask > 0; mask >>= 1) ssum += __shfl_xor(ssum, mask, 32);
  float fx = ex / fmaxf(ssum, 1e-30f);
  if (act) outp[n * NCLUS + j] = fx;
  fx16[n * 32 + j] = __float2bfloat16(act ? fx : 0.0f);
}

// ---- fallback fp32 kernels (atomic path, R6-proven) ----
__global__ void __launch_bounds__(256) k_gemm1s(const float* x, const float* W1,
                                                const float* dinv, float* G1) {
  __shared__ float Ws[IN_DIM * HID];
  int tid = threadIdx.x;
  for (int i = tid; i < IN_DIM * HID; i += 256) Ws[i] = W1[i];
  __syncthreads();
  int j = tid & 31, r = tid >> 5;
  int n = blockIdx.x * 8 + r;
  if (n >= N_NODES) return;
  const float* xr = x + (size_t)n * IN_DIM;
  float acc = 0.0f;
  #pragma unroll
  for (int k = 0; k < IN_DIM; k++) acc += xr[k] * Ws[k * HID + j];
  G1[n * 32 + j] = acc * dinv[n];
}

__global__ void __launch_bounds__(256) k_gemm2s(const float* h, const float* W2,
                                                const float* dinv, float* G2) {
  __shared__ float Ws[HID * 32];
  int tid = threadIdx.x;
  for (int i = tid; i < HID * 32; i += 256) Ws[i] = 0.0f;
  __syncthreads();
  for (int i = tid; i < HID * NCLUS; i += 256) {
    int k = i / NCLUS, j = i % NCLUS;
    Ws[k * 32 + j] = W2[i];
  }
  __syncthreads();
  int j = tid & 31, r = tid >> 5;
  int n = blockIdx.x * 8 + r;
  if (n >= N_NODES) return;
  const float* hr = h + (size_t)n * 32;
  float acc = 0.0f;
  #pragma unroll
  for (int k = 0; k < HID; k++) acc += hr[k] * Ws[k * 32 + j];
  G2[n * 32 + j] = (j < NCLUS) ? acc * dinv[n] : 0.0f;
}

__global__ void __launch_bounds__(256) k_eagg2(const int* ei, const int* flag,
                                               const float* G, float* D) {
  int j = threadIdx.x & 31, g = threadIdx.x >> 5;
  int f = *flag;
  for (int e = blockIdx.x * 8 + g; e < N_EDGES; e += gridDim.x * 8) {
    int s = edge_at(ei, 0, e, f);
    int d = edge_at(ei, 1, e, f);
    atomicAdd(&D[d * 32 + j], G[s * 32 + j]);
  }
}

__global__ void k_relu2(const float* A, const float* dinv, const float* b1, float* G) {
  int t = blockIdx.x * blockDim.x + threadIdx.x;
  if (t >= N_NODES * 32) return;
  int n = t >> 5, j = t & 31;
  G[t] = fmaxf(dinv[n] * (A[t] + G[t]) + b1[j], 0.0f);
}

__global__ void __launch_bounds__(256) k_softmax2(const float* S, const float* G2, const float* dinv,
                                                  const float* b2, float* outp) {
  int n = blockIdx.x * blockDim.x + threadIdx.x;
  if (n >= N_NODES) return;
  float di = dinv[n];
  float lg[NCLUS];
  float m = -1e30f;
  #pragma unroll
  for (int j = 0; j < NCLUS; j++) {
    float v = di * (S[n * 32 + j] + G2[n * 32 + j]) + b2[j];
    v = fminf(fmaxf(v, -80.0f), 80.0f);
    lg[j] = v; m = fmaxf(m, v);
  }
  float ssum = 0.0f;
  #pragma unroll
  for (int j = 0; j < NCLUS; j++) { lg[j] = __expf(lg[j] - m); ssum += lg[j]; }
  float inv = 1.0f / ssum;
  #pragma unroll
  for (int j = 0; j < NCLUS; j++) outp[n * NCLUS + j] = lg[j] * inv;
}

// ---- out (fp32, stride 30) -> fx16 (bf16, stride 32) ----
__global__ void k_fx16(const float* outp, __hip_bfloat16* fx16) {
  int t = blockIdx.x * blockDim.x + threadIdx.x;
  if (t >= N_NODES * 32) return;
  int n = t >> 5, j = t & 31;
  fx16[t] = __float2bfloat16((j < NCLUS) ? outp[n * NCLUS + j] : 0.0f);
}

// ---- edge MSE (bf16 fx16 gather, 64B-aligned rows; double-atomic total) ----
__global__ void __launch_bounds__(256) k_msef(const int* ei, const float* ep,
                                              const __hip_bfloat16* fx16, const int* flag,
                                              double* msed) {
  __shared__ float sd[256];
  int tid = threadIdx.x;
  int j = tid & 31, g = tid >> 5;
  int f = *flag;
  float local = 0.0f;
  for (int e = blockIdx.x * 8 + g; e < N_EDGES; e += gridDim.x * 8) {
    int s = edge_at(ei, 0, e, f);
    int d = edge_at(ei, 1, e, f);
    float v = bf2f(fx16[s * 32 + j]) * bf2f(fx16[d * 32 + j]);  // cols 30,31 are 0
    #pragma unroll
    for (int mask = 16; mask > 0; mask >>= 1) v += __shfl_xor(v, mask, 32);
    if (j == 0) { float diff = v - ep[e]; local += diff * diff; }
  }
  sd[tid] = local; __syncthreads();
  for (int off = 128; off > 0; off >>= 1) {
    if (tid < off) sd[tid] += sd[tid + off];
    __syncthreads();
  }
  if (tid == 0) atomicAdd(msed, (double)sd[0]);
}

// ---- column sums of log(1-FX^2) (fp32 FX from out, stride 30) ----
__global__ void __launch_bounds__(256) k_colsumf(const float* FX, float* colsum) {
  __shared__ float sd[256];
  int tid = threadIdx.x;
  int j = tid & 31, g = tid >> 5;
  float local = 0.0f;
  if (j < NCLUS) {
    for (int n = blockIdx.x * 8 + g; n < N_NODES; n += gridDim.x * 8) {
      float v = FX[n * NCLUS + j];
      local += log1pf(-v * v);
    }
  }
  sd[tid] = local; __syncthreads();
  if (tid < 32) {
    float s = 0.0f;
    #pragma unroll
    for (int gg = 0; gg < 8; gg++) s += sd[tid + 32 * gg];
    if (tid < NCLUS) atomicAdd(&colsum[tid], s);
  }
}

// ---- final loss (fp32 out, double mse) ----
__global__ void k_final(const float* colsum, const double* msed, float* out) {
  int tid = threadIdx.x;
  float v = 0.0f;
  if (tid < NCLUS) v = logf(1.0001f - __expf(colsum[tid]));
  #pragma unroll
  for (int mask = 32; mask > 0; mask >>= 1) v += __shfl_xor(v, mask, 64);
  if (tid == 0) {
    float preg = -v;
    float msev = (float)(*msed / (double)N_EDGES);
    out[(size_t)N_NODES * NCLUS] = msev + 0.01f * preg;
  }
}

extern "C" void kernel_launch(void* const* d_in, const int* in_sizes, int n_in,
                              void* d_out, int out_size, void* d_ws, size_t ws_size,
                              hipStream_t stream) {
  const float* x  = (const float*)d_in[0];
  const int*   ei = (const int*)d_in[1];
  const float* ep = (const float*)d_in[2];
  const float* W1 = (const float*)d_in[3];
  const float* b1 = (const float*)d_in[4];
  const float* W2 = (const float*)d_in[5];
  const float* b2 = (const float*)d_in[6];
  float* out = (float*)d_out;   // fp32: FX[100000*30] then loss scalar

  char* ws = (char*)d_ws;
  size_t off = 0;
  auto alloc = [&](size_t bytes) { size_t o = off; off += (bytes + 255) & ~(size_t)255; return o; };

  size_t o_hdr  = alloc(1024);                       // flag@0, msed@8(double), colsum@256, bsum@512
  size_t o_cnt  = alloc((size_t)N_NODES * 4);
  size_t o_dinv = alloc((size_t)N_NODES * 4);
  size_t o_B1   = alloc((size_t)N_NODES * 32 * 4);   // CSR: G1b/G2b (bf16) ; fallback: fp32 G
  size_t o_B2   = alloc((size_t)N_NODES * 32 * 4);   // CSR: h fp32, then fx16 ; fallback: fp32 D

  int*    flag   = (int*)(ws + o_hdr);
  double* msed   = (double*)(ws + o_hdr + 8);
  float*  colsum = (float*)(ws + o_hdr + 256);
  int*    bsum   = (int*)(ws + o_hdr + 512);
  int*    cnt    = (int*)(ws + o_cnt);
  float*  dinv   = (float*)(ws + o_dinv);
  float*  B1f    = (float*)(ws + o_B1);
  float*  B2f    = (float*)(ws + o_B2);
  __hip_bfloat16* B1b = (__hip_bfloat16*)(ws + o_B1);
  __hip_bfloat16* B2b = (__hip_bfloat16*)(ws + o_B2);

  const int nodeBlocks = (N_NODES + 255) / 256;
  const int edgeBlocks = (N_EDGES + 255) / 256;
  const int grpBlocks  = (N_NODES + 7) / 8;
  const int elemBlocks = (N_NODES * 32 + 255) / 256;

  k_detect<<<1, 64, 0, stream>>>((const unsigned int*)ei, flag);
  k_zero<<<nodeBlocks, 256, 0, stream>>>(cnt, colsum, msed);
  k_count<<<edgeBlocks, 256, 0, stream>>>(ei, flag, cnt);
  k_dinv<<<nodeBlocks, 256, 0, stream>>>(cnt, dinv);

  size_t o_cursor = alloc((size_t)N_NODES * 4);
  size_t o_csr    = alloc((size_t)N_EDGES * 4);
  bool use_csr = (off <= ws_size);   // R7 confirmed: this path runs (ws >= 40.3 MB)

  const __hip_bfloat16* fx16;

  if (use_csr) {
    int* cursor = (int*)(ws + o_cursor);
    int* csr    = (int*)(ws + o_csr);
    k_scan1<<<SCAN_NBLK, 256, 0, stream>>>(cnt, bsum);
    k_scan2<<<1, 64, 0, stream>>>(bsum);
    k_scan3<<<SCAN_NBLK, 256, 0, stream>>>(cnt, bsum, cursor);
    k_scatter<<<edgeBlocks, 256, 0, stream>>>(ei, flag, cursor, csr);

    __hip_bfloat16* G1b  = B1b;                       // 6.4 MB in B1
    float*          h    = B2f;                       // 12.8 MB in B2
    __hip_bfloat16* G2b  = B1b;                       // reuse B1 (G1 dead)
    __hip_bfloat16* fx   = B2b;                       // reuse B2 (h dead after gemm2b)

    k_gemm1b<<<grpBlocks, 256, 0, stream>>>(x, W1, dinv, G1b);
    k_agg1b<<<grpBlocks, 256, 0, stream>>>(G1b, cursor, cnt, csr, dinv, b1, h);
    k_gemm2b<<<grpBlocks, 256, 0, stream>>>(h, W2, dinv, G2b);
    k_agg2b<<<grpBlocks, 256, 0, stream>>>(G2b, cursor, cnt, csr, dinv, b2, out, fx);
    fx16 = fx;
  } else {
    // atomic fallback (fp32 G, pre-scaled)
    k_gemm1s<<<grpBlocks, 256, 0, stream>>>(x, W1, dinv, B1f);
    hipMemsetAsync(B2f, 0, (size_t)N_NODES * 32 * 4, stream);
    k_eagg2<<<8192, 256, 0, stream>>>(ei, flag, B1f, B2f);
    k_relu2<<<elemBlocks, 256, 0, stream>>>(B2f, dinv, b1, B1f);
    k_gemm2s<<<grpBlocks, 256, 0, stream>>>(B1f, W2, dinv, B2f);
    hipMemsetAsync(B1f, 0, (size_t)N_NODES * 32 * 4, stream);
    k_eagg2<<<8192, 256, 0, stream>>>(ei, flag, B2f, B1f);
    k_softmax2<<<nodeBlocks, 256, 0, stream>>>(B1f, B2f, dinv, b2, out);
    k_fx16<<<elemBlocks, 256, 0, stream>>>(out, B1b);  // B1 dead after softmax2
    fx16 = B1b;
  }

  // loss
  k_msef<<<4096, 256, 0, stream>>>(ei, ep, fx16, flag, msed);
  k_colsumf<<<256, 256, 0, stream>>>(out, colsum);
  k_final<<<1, 64, 0, stream>>>(colsum, msed, out);
}

// Round 9
// 801.843 us; speedup vs baseline: 1.6330x; 1.2884x over previous
//
#include <hip/hip_runtime.h>
#include <hip/hip_bf16.h>

#define N_NODES 100000
#define N_EDGES 3200000
#define IN_DIM  128
#define HID     32
#define NCLUS   30
#define SCAN_CHUNK 1024
#define SCAN_NBLK  98   // ceil(100000/1024)

__device__ __forceinline__ float bf2f(__hip_bfloat16 v) { return __bfloat162float(v); }

// edge_index accessor: f=0 -> int32 layout, f=1 -> int64 layout (read low word)
__device__ __forceinline__ int edge_at(const int* ei, int row, int e, int f) {
  int v = ei[(row * N_EDGES + e) << f];
  return min(max(v, 0), N_NODES - 1);
}

// ---- detect int32 vs int64 edge_index ----
__global__ void k_detect(const unsigned int* ei, int* flag) {
  if (threadIdx.x == 0) {
    int zeros = 0;
    for (int i = 1; i < 128; i += 2) zeros += (ei[i] == 0u) ? 1 : 0;
    *flag = (zeros >= 48) ? 1 : 0;
  }
}

// ---- zero init ----
__global__ void k_zero(int* cnt, float* colsum, double* msed) {
  int t = blockIdx.x * blockDim.x + threadIdx.x;
  if (t < N_NODES) cnt[t] = 0;
  if (t < 32) colsum[t] = 0.0f;
  if (t == 0) *msed = 0.0;
}

// ---- in-degree count + per-edge rank (rank write is coalesced) ----
__global__ void k_countrank(const int* ei, const int* flag, int* cnt, int* rank) {
  int e = blockIdx.x * blockDim.x + threadIdx.x;
  if (e >= N_EDGES) return;
  int f = *flag;
  int d = edge_at(ei, 1, e, f);
  rank[e] = atomicAdd(&cnt[d], 1);
}

// ---- plain count (fallback path, no rank array needed) ----
__global__ void k_count(const int* ei, const int* flag, int* cnt) {
  int e = blockIdx.x * blockDim.x + threadIdx.x;
  if (e >= N_EDGES) return;
  int f = *flag;
  atomicAdd(&cnt[edge_at(ei, 1, e, f)], 1);
}

// ---- dinv[n] = rsqrt(in_deg + 1) ----
__global__ void k_dinv(const int* cnt, float* dinv) {
  int t = blockIdx.x * blockDim.x + threadIdx.x;
  if (t < N_NODES) dinv[t] = rsqrtf((float)(cnt[t] + 1));
}

// ---- scan stage 1 ----
__global__ void k_scan1(const int* cnt, int* bsum) {
  __shared__ int sd[256];
  int tid = threadIdx.x;
  int base = blockIdx.x * SCAN_CHUNK;
  int s = 0;
  for (int i = tid; i < SCAN_CHUNK; i += 256) {
    int idx = base + i;
    s += (idx < N_NODES) ? cnt[idx] : 0;
  }
  sd[tid] = s; __syncthreads();
  for (int off = 128; off > 0; off >>= 1) {
    if (tid < off) sd[tid] += sd[tid + off];
    __syncthreads();
  }
  if (tid == 0) bsum[blockIdx.x] = sd[0];
}

// ---- scan stage 2 ----
__global__ void k_scan2(int* bsum) {
  if (threadIdx.x == 0) {
    int run = 0;
    for (int i = 0; i < SCAN_NBLK; i++) { int t = bsum[i]; bsum[i] = run; run += t; }
  }
}

// ---- scan stage 3: cursor = exclusive prefix of cnt (row START; never bumped) ----
__global__ void k_scan3(const int* cnt, const int* bsum, int* cursor) {
  __shared__ int ts[256];
  int tid = threadIdx.x;
  int base = blockIdx.x * SCAN_CHUNK + tid * 4;
  int v[4]; int s = 0;
  #pragma unroll
  for (int j = 0; j < 4; j++) {
    int idx = base + j;
    v[j] = (idx < N_NODES) ? cnt[idx] : 0;
    s += v[j];
  }
  ts[tid] = s; __syncthreads();
  for (int off = 1; off < 256; off <<= 1) {
    int t = (tid >= off) ? ts[tid - off] : 0;
    __syncthreads();
    ts[tid] += t;
    __syncthreads();
  }
  int excl = bsum[blockIdx.x] + (tid > 0 ? ts[tid - 1] : 0);
  #pragma unroll
  for (int j = 0; j < 4; j++) {
    int idx = base + j;
    if (idx < N_NODES) { cursor[idx] = excl; excl += v[j]; }
  }
}

// ---- CSR scatter, atomic-free: csr[cursor[d] + rank[e]] = s ----
__global__ void k_scatter2(const int* ei, const int* flag, const int* cursor,
                           const int* rank, int* csr_src) {
  int e = blockIdx.x * blockDim.x + threadIdx.x;
  if (e >= N_EDGES) return;
  int f = *flag;
  int s = edge_at(ei, 0, e, f);
  int d = edge_at(ei, 1, e, f);
  csr_src[cursor[d] + rank[e]] = s;
}

// ---- GEMM1 scaled -> bf16 ----
__global__ void __launch_bounds__(256) k_gemm1b(const float* x, const float* W1,
                                                const float* dinv, __hip_bfloat16* G1) {
  __shared__ float Ws[IN_DIM * HID];
  int tid = threadIdx.x;
  for (int i = tid; i < IN_DIM * HID; i += 256) Ws[i] = W1[i];
  __syncthreads();
  int j = tid & 31, r = tid >> 5;
  int n = blockIdx.x * 8 + r;
  if (n >= N_NODES) return;
  const float* xr = x + (size_t)n * IN_DIM;
  float acc = 0.0f;
  #pragma unroll
  for (int k = 0; k < IN_DIM; k++) acc += xr[k] * Ws[k * HID + j];
  G1[n * 32 + j] = __float2bfloat16(acc * dinv[n]);
}

// ---- CSR agg layer1 (bf16 gather): h = relu(dinv*(G1[n]+sum G1[s]) + b1), fp32 ----
__global__ void __launch_bounds__(256) k_agg1b(const __hip_bfloat16* G, const int* cursor,
                                               const int* cnt, const int* csr, const float* dinv,
                                               const float* b1, float* h) {
  int j = threadIdx.x & 31, g = threadIdx.x >> 5;
  int n = blockIdx.x * 8 + g;
  if (n >= N_NODES) return;
  int len = cnt[n];
  int st = cursor[n];          // cursor = row start (atomic-free scatter)
  float acc = bf2f(G[n * 32 + j]);
  int i = 0;
  for (; i + 4 <= len; i += 4) {
    int s0 = csr[st + i], s1 = csr[st + i + 1], s2 = csr[st + i + 2], s3 = csr[st + i + 3];
    float v0 = bf2f(G[s0 * 32 + j]), v1 = bf2f(G[s1 * 32 + j]);
    float v2 = bf2f(G[s2 * 32 + j]), v3 = bf2f(G[s3 * 32 + j]);
    acc += (v0 + v1) + (v2 + v3);
  }
  for (; i < len; i++) acc += bf2f(G[csr[st + i] * 32 + j]);
  h[n * 32 + j] = fmaxf(dinv[n] * acc + b1[j], 0.0f);
}

// ---- GEMM2 scaled -> bf16; cols 30,31 = 0 ----
__global__ void __launch_bounds__(256) k_gemm2b(const float* h, const float* W2,
                                                const float* dinv, __hip_bfloat16* G2) {
  __shared__ float Ws[HID * 32];
  int tid = threadIdx.x;
  for (int i = tid; i < HID * 32; i += 256) Ws[i] = 0.0f;
  __syncthreads();
  for (int i = tid; i < HID * NCLUS; i += 256) {
    int k = i / NCLUS, j = i % NCLUS;
    Ws[k * 32 + j] = W2[i];
  }
  __syncthreads();
  int j = tid & 31, r = tid >> 5;
  int n = blockIdx.x * 8 + r;
  if (n >= N_NODES) return;
  const float* hr = h + (size_t)n * 32;
  float acc = 0.0f;
  #pragma unroll
  for (int k = 0; k < HID; k++) acc += hr[k] * Ws[k * 32 + j];
  G2[n * 32 + j] = __float2bfloat16((j < NCLUS) ? acc * dinv[n] : 0.0f);
}

// ---- CSR agg layer2 (bf16 gather) + softmax -> out (fp32) + fx16 (bf16, 32-padded) ----
__global__ void __launch_bounds__(256) k_agg2b(const __hip_bfloat16* G, const int* cursor,
                                               const int* cnt, const int* csr, const float* dinv,
                                               const float* b2, float* outp, __hip_bfloat16* fx16) {
  int j = threadIdx.x & 31, g = threadIdx.x >> 5;
  int n = blockIdx.x * 8 + g;
  if (n >= N_NODES) return;
  int len = cnt[n];
  int st = cursor[n];
  float acc = bf2f(G[n * 32 + j]);
  int i = 0;
  for (; i + 4 <= len; i += 4) {
    int s0 = csr[st + i], s1 = csr[st + i + 1], s2 = csr[st + i + 2], s3 = csr[st + i + 3];
    float v0 = bf2f(G[s0 * 32 + j]), v1 = bf2f(G[s1 * 32 + j]);
    float v2 = bf2f(G[s2 * 32 + j]), v3 = bf2f(G[s3 * 32 + j]);
    acc += (v0 + v1) + (v2 + v3);
  }
  for (; i < len; i++) acc += bf2f(G[csr[st + i] * 32 + j]);
  bool act = (j < NCLUS);
  float logit = act ? fminf(fmaxf(dinv[n] * acc + b2[j], -80.0f), 80.0f) : -1e30f;
  float m = logit;
  #pragma unroll
  for (int mask = 16; mask > 0; mask >>= 1) m = fmaxf(m, __shfl_xor(m, mask, 32));
  float ex = act ? __expf(logit - m) : 0.0f;
  float ssum = ex;
  #pragma unroll
  for (int mask = 16; mask > 0; mask >>= 1) ssum += __shfl_xor(ssum, mask, 32);
  float fx = ex / fmaxf(ssum, 1e-30f);
  if (act) outp[n * NCLUS + j] = fx;
  fx16[n * 32 + j] = __float2bfloat16(act ? fx : 0.0f);
}

// ---- fallback fp32 kernels (atomic path, R6-proven) ----
__global__ void __launch_bounds__(256) k_gemm1s(const float* x, const float* W1,
                                                const float* dinv, float* G1) {
  __shared__ float Ws[IN_DIM * HID];
  int tid = threadIdx.x;
  for (int i = tid; i < IN_DIM * HID; i += 256) Ws[i] = W1[i];
  __syncthreads();
  int j = tid & 31, r = tid >> 5;
  int n = blockIdx.x * 8 + r;
  if (n >= N_NODES) return;
  const float* xr = x + (size_t)n * IN_DIM;
  float acc = 0.0f;
  #pragma unroll
  for (int k = 0; k < IN_DIM; k++) acc += xr[k] * Ws[k * HID + j];
  G1[n * 32 + j] = acc * dinv[n];
}

__global__ void __launch_bounds__(256) k_gemm2s(const float* h, const float* W2,
                                                const float* dinv, float* G2) {
  __shared__ float Ws[HID * 32];
  int tid = threadIdx.x;
  for (int i = tid; i < HID * 32; i += 256) Ws[i] = 0.0f;
  __syncthreads();
  for (int i = tid; i < HID * NCLUS; i += 256) {
    int k = i / NCLUS, j = i % NCLUS;
    Ws[k * 32 + j] = W2[i];
  }
  __syncthreads();
  int j = tid & 31, r = tid >> 5;
  int n = blockIdx.x * 8 + r;
  if (n >= N_NODES) return;
  const float* hr = h + (size_t)n * 32;
  float acc = 0.0f;
  #pragma unroll
  for (int k = 0; k < HID; k++) acc += hr[k] * Ws[k * 32 + j];
  G2[n * 32 + j] = (j < NCLUS) ? acc * dinv[n] : 0.0f;
}

__global__ void __launch_bounds__(256) k_eagg2(const int* ei, const int* flag,
                                               const float* G, float* D) {
  int j = threadIdx.x & 31, g = threadIdx.x >> 5;
  int f = *flag;
  for (int e = blockIdx.x * 8 + g; e < N_EDGES; e += gridDim.x * 8) {
    int s = edge_at(ei, 0, e, f);
    int d = edge_at(ei, 1, e, f);
    atomicAdd(&D[d * 32 + j], G[s * 32 + j]);
  }
}

__global__ void k_relu2(const float* A, const float* dinv, const float* b1, float* G) {
  int t = blockIdx.x * blockDim.x + threadIdx.x;
  if (t >= N_NODES * 32) return;
  int n = t >> 5, j = t & 31;
  G[t] = fmaxf(dinv[n] * (A[t] + G[t]) + b1[j], 0.0f);
}

__global__ void __launch_bounds__(256) k_softmax2(const float* S, const float* G2, const float* dinv,
                                                  const float* b2, float* outp) {
  int n = blockIdx.x * blockDim.x + threadIdx.x;
  if (n >= N_NODES) return;
  float di = dinv[n];
  float lg[NCLUS];
  float m = -1e30f;
  #pragma unroll
  for (int j = 0; j < NCLUS; j++) {
    float v = di * (S[n * 32 + j] + G2[n * 32 + j]) + b2[j];
    v = fminf(fmaxf(v, -80.0f), 80.0f);
    lg[j] = v; m = fmaxf(m, v);
  }
  float ssum = 0.0f;
  #pragma unroll
  for (int j = 0; j < NCLUS; j++) { lg[j] = __expf(lg[j] - m); ssum += lg[j]; }
  float inv = 1.0f / ssum;
  #pragma unroll
  for (int j = 0; j < NCLUS; j++) outp[n * NCLUS + j] = lg[j] * inv;
}

// ---- out (fp32, stride 30) -> fx16 (bf16, stride 32) ----
__global__ void k_fx16(const float* outp, __hip_bfloat16* fx16) {
  int t = blockIdx.x * blockDim.x + threadIdx.x;
  if (t >= N_NODES * 32) return;
  int n = t >> 5, j = t & 31;
  fx16[t] = __float2bfloat16((j < NCLUS) ? outp[n * NCLUS + j] : 0.0f);
}

// ---- edge MSE (bf16 fx16 gather, 64B-aligned rows; double-atomic total) ----
__global__ void __launch_bounds__(256) k_msef(const int* ei, const float* ep,
                                              const __hip_bfloat16* fx16, const int* flag,
                                              double* msed) {
  __shared__ float sd[256];
  int tid = threadIdx.x;
  int j = tid & 31, g = tid >> 5;
  int f = *flag;
  float local = 0.0f;
  for (int e = blockIdx.x * 8 + g; e < N_EDGES; e += gridDim.x * 8) {
    int s = edge_at(ei, 0, e, f);
    int d = edge_at(ei, 1, e, f);
    float v = bf2f(fx16[s * 32 + j]) * bf2f(fx16[d * 32 + j]);  // cols 30,31 are 0
    #pragma unroll
    for (int mask = 16; mask > 0; mask >>= 1) v += __shfl_xor(v, mask, 32);
    if (j == 0) { float diff = v - ep[e]; local += diff * diff; }
  }
  sd[tid] = local; __syncthreads();
  for (int off = 128; off > 0; off >>= 1) {
    if (tid < off) sd[tid] += sd[tid + off];
    __syncthreads();
  }
  if (tid == 0) atomicAdd(msed, (double)sd[0]);
}

// ---- column sums of log(1-FX^2) (fp32 FX from out, stride 30) ----
__global__ void __launch_bounds__(256) k_colsumf(const float* FX, float* colsum) {
  __shared__ float sd[256];
  int tid = threadIdx.x;
  int j = tid & 31, g = tid >> 5;
  float local = 0.0f;
  if (j < NCLUS) {
    for (int n = blockIdx.x * 8 + g; n < N_NODES; n += gridDim.x * 8) {
      float v = FX[n * NCLUS + j];
      local += log1pf(-v * v);
    }
  }
  sd[tid] = local; __syncthreads();
  if (tid < 32) {
    float s = 0.0f;
    #pragma unroll
    for (int gg = 0; gg < 8; gg++) s += sd[tid + 32 * gg];
    if (tid < NCLUS) atomicAdd(&colsum[tid], s);
  }
}

// ---- final loss ----
__global__ void k_final(const float* colsum, const double* msed, float* out) {
  int tid = threadIdx.x;
  float v = 0.0f;
  if (tid < NCLUS) v = logf(1.0001f - __expf(colsum[tid]));
  #pragma unroll
  for (int mask = 32; mask > 0; mask >>= 1) v += __shfl_xor(v, mask, 64);
  if (tid == 0) {
    float preg = -v;
    float msev = (float)(*msed / (double)N_EDGES);
    out[(size_t)N_NODES * NCLUS] = msev + 0.01f * preg;
  }
}

extern "C" void kernel_launch(void* const* d_in, const int* in_sizes, int n_in,
                              void* d_out, int out_size, void* d_ws, size_t ws_size,
                              hipStream_t stream) {
  const float* x  = (const float*)d_in[0];
  const int*   ei = (const int*)d_in[1];
  const float* ep = (const float*)d_in[2];
  const float* W1 = (const float*)d_in[3];
  const float* b1 = (const float*)d_in[4];
  const float* W2 = (const float*)d_in[5];
  const float* b2 = (const float*)d_in[6];
  float* out = (float*)d_out;   // fp32: FX[100000*30] then loss scalar

  char* ws = (char*)d_ws;
  size_t off = 0;
  auto alloc = [&](size_t bytes) { size_t o = off; off += (bytes + 255) & ~(size_t)255; return o; };

  size_t o_hdr  = alloc(1024);                       // flag@0, msed@8(double), colsum@256, bsum@512
  size_t o_cnt  = alloc((size_t)N_NODES * 4);
  size_t o_dinv = alloc((size_t)N_NODES * 4);
  size_t o_B1   = alloc((size_t)N_NODES * 32 * 4);   // CSR: G1b/G2b (bf16) ; fallback: fp32 G
  size_t o_B2   = alloc((size_t)N_NODES * 32 * 4);   // CSR: rank -> h fp32 -> fx16 ; fallback: fp32 D

  int*    flag   = (int*)(ws + o_hdr);
  double* msed   = (double*)(ws + o_hdr + 8);
  float*  colsum = (float*)(ws + o_hdr + 256);
  int*    bsum   = (int*)(ws + o_hdr + 512);
  int*    cnt    = (int*)(ws + o_cnt);
  float*  dinv   = (float*)(ws + o_dinv);
  float*  B1f    = (float*)(ws + o_B1);
  float*  B2f    = (float*)(ws + o_B2);
  __hip_bfloat16* B1b = (__hip_bfloat16*)(ws + o_B1);
  __hip_bfloat16* B2b = (__hip_bfloat16*)(ws + o_B2);

  const int nodeBlocks = (N_NODES + 255) / 256;
  const int edgeBlocks = (N_EDGES + 255) / 256;
  const int grpBlocks  = (N_NODES + 7) / 8;
  const int elemBlocks = (N_NODES * 32 + 255) / 256;

  k_detect<<<1, 64, 0, stream>>>((const unsigned int*)ei, flag);

  size_t o_cursor = alloc((size_t)N_NODES * 4);
  size_t o_csr    = alloc((size_t)N_EDGES * 4);
  bool use_csr = (off <= ws_size);   // confirmed running since R7 (ws >= 40.3 MB)

  const __hip_bfloat16* fx16;

  if (use_csr) {
    int* cursor = (int*)(ws + o_cursor);
    int* csr    = (int*)(ws + o_csr);
    int* rank   = (int*)(ws + o_B2);   // N_EDGES*4 == N_NODES*32*4; dead until agg1b writes h

    k_zero<<<nodeBlocks, 256, 0, stream>>>(cnt, colsum, msed);
    k_countrank<<<edgeBlocks, 256, 0, stream>>>(ei, flag, cnt, rank);
    k_dinv<<<nodeBlocks, 256, 0, stream>>>(cnt, dinv);
    k_scan1<<<SCAN_NBLK, 256, 0, stream>>>(cnt, bsum);
    k_scan2<<<1, 64, 0, stream>>>(bsum);
    k_scan3<<<SCAN_NBLK, 256, 0, stream>>>(cnt, bsum, cursor);
    k_scatter2<<<edgeBlocks, 256, 0, stream>>>(ei, flag, cursor, rank, csr);

    __hip_bfloat16* G1b  = B1b;
    float*          h    = B2f;        // overwrites rank (dead after scatter2)
    __hip_bfloat16* G2b  = B1b;
    __hip_bfloat16* fx   = B2b;

    k_gemm1b<<<grpBlocks, 256, 0, stream>>>(x, W1, dinv, G1b);
    k_agg1b<<<grpBlocks, 256, 0, stream>>>(G1b, cursor, cnt, csr, dinv, b1, h);
    k_gemm2b<<<grpBlocks, 256, 0, stream>>>(h, W2, dinv, G2b);
    k_agg2b<<<grpBlocks, 256, 0, stream>>>(G2b, cursor, cnt, csr, dinv, b2, out, fx);
    fx16 = fx;
  } else {
    k_zero<<<nodeBlocks, 256, 0, stream>>>(cnt, colsum, msed);
    k_count<<<edgeBlocks, 256, 0, stream>>>(ei, flag, cnt);
    k_dinv<<<nodeBlocks, 256, 0, stream>>>(cnt, dinv);
    k_gemm1s<<<grpBlocks, 256, 0, stream>>>(x, W1, dinv, B1f);
    hipMemsetAsync(B2f, 0, (size_t)N_NODES * 32 * 4, stream);
    k_eagg2<<<8192, 256, 0, stream>>>(ei, flag, B1f, B2f);
    k_relu2<<<elemBlocks, 256, 0, stream>>>(B2f, dinv, b1, B1f);
    k_gemm2s<<<grpBlocks, 256, 0, stream>>>(B1f, W2, dinv, B2f);
    hipMemsetAsync(B1f, 0, (size_t)N_NODES * 32 * 4, stream);
    k_eagg2<<<8192, 256, 0, stream>>>(ei, flag, B2f, B1f);
    k_softmax2<<<nodeBlocks, 256, 0, stream>>>(B1f, B2f, dinv, b2, out);
    k_fx16<<<elemBlocks, 256, 0, stream>>>(out, B1b);
    fx16 = B1b;
  }

  // loss
  k_msef<<<4096, 256, 0, stream>>>(ei, ep, fx16, flag, msed);
  k_colsumf<<<256, 256, 0, stream>>>(out, colsum);
  k_final<<<1, 64, 0, stream>>>(colsum, msed, out);
}

// Round 10
// 649.406 us; speedup vs baseline: 2.0164x; 1.2347x over previous
//
#include <hip/hip_runtime.h>
#include <hip/hip_bf16.h>

#define N_NODES 100000
#define N_EDGES 3200000
#define IN_DIM  128
#define HID     32
#define NCLUS   30
#define SCAN_CHUNK 1024
#define SCAN_NBLK  98   // ceil(100000/1024)

__device__ __forceinline__ float bf2f(__hip_bfloat16 v) { return __bfloat162float(v); }

// dot of two packed-bf16 words (2 elems each), exact in fp32
__device__ __forceinline__ float dotw(unsigned a, unsigned b) {
  float r;
  r  = __uint_as_float(a << 16)          * __uint_as_float(b << 16);
  r += __uint_as_float(a & 0xffff0000u)  * __uint_as_float(b & 0xffff0000u);
  return r;
}

// edge_index accessor: f=0 -> int32 layout, f=1 -> int64 layout (read low word)
__device__ __forceinline__ int edge_at(const int* ei, int row, int e, int f) {
  int v = ei[(row * N_EDGES + e) << f];
  return min(max(v, 0), N_NODES - 1);
}

// ---- detect int32 vs int64 edge_index ----
__global__ void k_detect(const unsigned int* ei, int* flag) {
  if (threadIdx.x == 0) {
    int zeros = 0;
    for (int i = 1; i < 128; i += 2) zeros += (ei[i] == 0u) ? 1 : 0;
    *flag = (zeros >= 48) ? 1 : 0;
  }
}

// ---- zero init ----
__global__ void k_zero(int* cnt, float* colsum, double* msed) {
  int t = blockIdx.x * blockDim.x + threadIdx.x;
  if (t < N_NODES) cnt[t] = 0;
  if (t < 32) colsum[t] = 0.0f;
  if (t == 0) *msed = 0.0;
}

// ---- in-degree count + per-edge rank ----
__global__ void k_countrank(const int* ei, const int* flag, int* cnt, int* rank) {
  int e = blockIdx.x * blockDim.x + threadIdx.x;
  if (e >= N_EDGES) return;
  int f = *flag;
  int d = edge_at(ei, 1, e, f);
  rank[e] = atomicAdd(&cnt[d], 1);
}

// ---- plain count (fallback path) ----
__global__ void k_count(const int* ei, const int* flag, int* cnt) {
  int e = blockIdx.x * blockDim.x + threadIdx.x;
  if (e >= N_EDGES) return;
  int f = *flag;
  atomicAdd(&cnt[edge_at(ei, 1, e, f)], 1);
}

// ---- dinv ----
__global__ void k_dinv(const int* cnt, float* dinv) {
  int t = blockIdx.x * blockDim.x + threadIdx.x;
  if (t < N_NODES) dinv[t] = rsqrtf((float)(cnt[t] + 1));
}

// ---- scan stage 1 ----
__global__ void k_scan1(const int* cnt, int* bsum) {
  __shared__ int sd[256];
  int tid = threadIdx.x;
  int base = blockIdx.x * SCAN_CHUNK;
  int s = 0;
  for (int i = tid; i < SCAN_CHUNK; i += 256) {
    int idx = base + i;
    s += (idx < N_NODES) ? cnt[idx] : 0;
  }
  sd[tid] = s; __syncthreads();
  for (int off = 128; off > 0; off >>= 1) {
    if (tid < off) sd[tid] += sd[tid + off];
    __syncthreads();
  }
  if (tid == 0) bsum[blockIdx.x] = sd[0];
}

// ---- scan stage 2 ----
__global__ void k_scan2(int* bsum) {
  if (threadIdx.x == 0) {
    int run = 0;
    for (int i = 0; i < SCAN_NBLK; i++) { int t = bsum[i]; bsum[i] = run; run += t; }
  }
}

// ---- scan stage 3: cursor = exclusive prefix (row START) ----
__global__ void k_scan3(const int* cnt, const int* bsum, int* cursor) {
  __shared__ int ts[256];
  int tid = threadIdx.x;
  int base = blockIdx.x * SCAN_CHUNK + tid * 4;
  int v[4]; int s = 0;
  #pragma unroll
  for (int j = 0; j < 4; j++) {
    int idx = base + j;
    v[j] = (idx < N_NODES) ? cnt[idx] : 0;
    s += v[j];
  }
  ts[tid] = s; __syncthreads();
  for (int off = 1; off < 256; off <<= 1) {
    int t = (tid >= off) ? ts[tid - off] : 0;
    __syncthreads();
    ts[tid] += t;
    __syncthreads();
  }
  int excl = bsum[blockIdx.x] + (tid > 0 ? ts[tid - 1] : 0);
  #pragma unroll
  for (int j = 0; j < 4; j++) {
    int idx = base + j;
    if (idx < N_NODES) { cursor[idx] = excl; excl += v[j]; }
  }
}

// ---- CSR scatter, atomic-free ----
__global__ void k_scatter2(const int* ei, const int* flag, const int* cursor,
                           const int* rank, int* csr_src) {
  int e = blockIdx.x * blockDim.x + threadIdx.x;
  if (e >= N_EDGES) return;
  int f = *flag;
  int s = edge_at(ei, 0, e, f);
  int d = edge_at(ei, 1, e, f);
  csr_src[cursor[d] + rank[e]] = s;
}

// ---- GEMM1 scaled -> bf16 ----
__global__ void __launch_bounds__(256) k_gemm1b(const float* x, const float* W1,
                                                const float* dinv, __hip_bfloat16* G1) {
  __shared__ float Ws[IN_DIM * HID];
  int tid = threadIdx.x;
  for (int i = tid; i < IN_DIM * HID; i += 256) Ws[i] = W1[i];
  __syncthreads();
  int j = tid & 31, r = tid >> 5;
  int n = blockIdx.x * 8 + r;
  if (n >= N_NODES) return;
  const float* xr = x + (size_t)n * IN_DIM;
  float acc = 0.0f;
  #pragma unroll
  for (int k = 0; k < IN_DIM; k++) acc += xr[k] * Ws[k * HID + j];
  G1[n * 32 + j] = __float2bfloat16(acc * dinv[n]);
}

// ---- CSR agg layer1 (bf16 gather) ----
__global__ void __launch_bounds__(256) k_agg1b(const __hip_bfloat16* G, const int* cursor,
                                               const int* cnt, const int* csr, const float* dinv,
                                               const float* b1, float* h) {
  int j = threadIdx.x & 31, g = threadIdx.x >> 5;
  int n = blockIdx.x * 8 + g;
  if (n >= N_NODES) return;
  int len = cnt[n];
  int st = cursor[n];
  float acc = bf2f(G[n * 32 + j]);
  int i = 0;
  for (; i + 4 <= len; i += 4) {
    int s0 = csr[st + i], s1 = csr[st + i + 1], s2 = csr[st + i + 2], s3 = csr[st + i + 3];
    float v0 = bf2f(G[s0 * 32 + j]), v1 = bf2f(G[s1 * 32 + j]);
    float v2 = bf2f(G[s2 * 32 + j]), v3 = bf2f(G[s3 * 32 + j]);
    acc += (v0 + v1) + (v2 + v3);
  }
  for (; i < len; i++) acc += bf2f(G[csr[st + i] * 32 + j]);
  h[n * 32 + j] = fmaxf(dinv[n] * acc + b1[j], 0.0f);
}

// ---- GEMM2 scaled -> bf16; cols 30,31 = 0 ----
__global__ void __launch_bounds__(256) k_gemm2b(const float* h, const float* W2,
                                                const float* dinv, __hip_bfloat16* G2) {
  __shared__ float Ws[HID * 32];
  int tid = threadIdx.x;
  for (int i = tid; i < HID * 32; i += 256) Ws[i] = 0.0f;
  __syncthreads();
  for (int i = tid; i < HID * NCLUS; i += 256) {
    int k = i / NCLUS, j = i % NCLUS;
    Ws[k * 32 + j] = W2[i];
  }
  __syncthreads();
  int j = tid & 31, r = tid >> 5;
  int n = blockIdx.x * 8 + r;
  if (n >= N_NODES) return;
  const float* hr = h + (size_t)n * 32;
  float acc = 0.0f;
  #pragma unroll
  for (int k = 0; k < HID; k++) acc += hr[k] * Ws[k * 32 + j];
  G2[n * 32 + j] = __float2bfloat16((j < NCLUS) ? acc * dinv[n] : 0.0f);
}

// ---- CSR agg layer2 (bf16 gather) + softmax -> out (fp32) + fx16 (bf16, 32-padded) ----
__global__ void __launch_bounds__(256) k_agg2b(const __hip_bfloat16* G, const int* cursor,
                                               const int* cnt, const int* csr, const float* dinv,
                                               const float* b2, float* outp, __hip_bfloat16* fx16) {
  int j = threadIdx.x & 31, g = threadIdx.x >> 5;
  int n = blockIdx.x * 8 + g;
  if (n >= N_NODES) return;
  int len = cnt[n];
  int st = cursor[n];
  float acc = bf2f(G[n * 32 + j]);
  int i = 0;
  for (; i + 4 <= len; i += 4) {
    int s0 = csr[st + i], s1 = csr[st + i + 1], s2 = csr[st + i + 2], s3 = csr[st + i + 3];
    float v0 = bf2f(G[s0 * 32 + j]), v1 = bf2f(G[s1 * 32 + j]);
    float v2 = bf2f(G[s2 * 32 + j]), v3 = bf2f(G[s3 * 32 + j]);
    acc += (v0 + v1) + (v2 + v3);
  }
  for (; i < len; i++) acc += bf2f(G[csr[st + i] * 32 + j]);
  bool act = (j < NCLUS);
  float logit = act ? fminf(fmaxf(dinv[n] * acc + b2[j], -80.0f), 80.0f) : -1e30f;
  float m = logit;
  #pragma unroll
  for (int mask = 16; mask > 0; mask >>= 1) m = fmaxf(m, __shfl_xor(m, mask, 32));
  float ex = act ? __expf(logit - m) : 0.0f;
  float ssum = ex;
  #pragma unroll
  for (int mask = 16; mask > 0; mask >>= 1) ssum += __shfl_xor(ssum, mask, 32);
  float fx = ex / fmaxf(ssum, 1e-30f);
  if (act) outp[n * NCLUS + j] = fx;
  fx16[n * 32 + j] = __float2bfloat16(act ? fx : 0.0f);
}

// ---- fallback fp32 kernels (atomic path) ----
__global__ void __launch_bounds__(256) k_gemm1s(const float* x, const float* W1,
                                                const float* dinv, float* G1) {
  __shared__ float Ws[IN_DIM * HID];
  int tid = threadIdx.x;
  for (int i = tid; i < IN_DIM * HID; i += 256) Ws[i] = W1[i];
  __syncthreads();
  int j = tid & 31, r = tid >> 5;
  int n = blockIdx.x * 8 + r;
  if (n >= N_NODES) return;
  const float* xr = x + (size_t)n * IN_DIM;
  float acc = 0.0f;
  #pragma unroll
  for (int k = 0; k < IN_DIM; k++) acc += xr[k] * Ws[k * HID + j];
  G1[n * 32 + j] = acc * dinv[n];
}

__global__ void __launch_bounds__(256) k_gemm2s(const float* h, const float* W2,
                                                const float* dinv, float* G2) {
  __shared__ float Ws[HID * 32];
  int tid = threadIdx.x;
  for (int i = tid; i < HID * 32; i += 256) Ws[i] = 0.0f;
  __syncthreads();
  for (int i = tid; i < HID * NCLUS; i += 256) {
    int k = i / NCLUS, j = i % NCLUS;
    Ws[k * 32 + j] = W2[i];
  }
  __syncthreads();
  int j = tid & 31, r = tid >> 5;
  int n = blockIdx.x * 8 + r;
  if (n >= N_NODES) return;
  const float* hr = h + (size_t)n * 32;
  float acc = 0.0f;
  #pragma unroll
  for (int k = 0; k < HID; k++) acc += hr[k] * Ws[k * 32 + j];
  G2[n * 32 + j] = (j < NCLUS) ? acc * dinv[n] : 0.0f;
}

__global__ void __launch_bounds__(256) k_eagg2(const int* ei, const int* flag,
                                               const float* G, float* D) {
  int j = threadIdx.x & 31, g = threadIdx.x >> 5;
  int f = *flag;
  for (int e = blockIdx.x * 8 + g; e < N_EDGES; e += gridDim.x * 8) {
    int s = edge_at(ei, 0, e, f);
    int d = edge_at(ei, 1, e, f);
    atomicAdd(&D[d * 32 + j], G[s * 32 + j]);
  }
}

__global__ void k_relu2(const float* A, const float* dinv, const float* b1, float* G) {
  int t = blockIdx.x * blockDim.x + threadIdx.x;
  if (t >= N_NODES * 32) return;
  int n = t >> 5, j = t & 31;
  G[t] = fmaxf(dinv[n] * (A[t] + G[t]) + b1[j], 0.0f);
}

__global__ void __launch_bounds__(256) k_softmax2(const float* S, const float* G2, const float* dinv,
                                                  const float* b2, float* outp) {
  int n = blockIdx.x * blockDim.x + threadIdx.x;
  if (n >= N_NODES) return;
  float di = dinv[n];
  float lg[NCLUS];
  float m = -1e30f;
  #pragma unroll
  for (int j = 0; j < NCLUS; j++) {
    float v = di * (S[n * 32 + j] + G2[n * 32 + j]) + b2[j];
    v = fminf(fmaxf(v, -80.0f), 80.0f);
    lg[j] = v; m = fmaxf(m, v);
  }
  float ssum = 0.0f;
  #pragma unroll
  for (int j = 0; j < NCLUS; j++) { lg[j] = __expf(lg[j] - m); ssum += lg[j]; }
  float inv = 1.0f / ssum;
  #pragma unroll
  for (int j = 0; j < NCLUS; j++) outp[n * NCLUS + j] = lg[j] * inv;
}

// ---- out (fp32, stride 30) -> fx16 (bf16, stride 32) ----
__global__ void k_fx16(const float* outp, __hip_bfloat16* fx16) {
  int t = blockIdx.x * blockDim.x + threadIdx.x;
  if (t >= N_NODES * 32) return;
  int n = t >> 5, j = t & 31;
  fx16[t] = __float2bfloat16((j < NCLUS) ? outp[n * NCLUS + j] : 0.0f);
}

// ---- edge MSE, lane-per-edge: in-lane packed-bf16 dot over 64B rows ----
__global__ void __launch_bounds__(256) k_msef2(const int* ei, const float* ep,
                                               const uint4* fx16, const int* flag,
                                               double* msed) {
  int f = *flag;
  int tid = blockIdx.x * blockDim.x + threadIdx.x;
  float local = 0.0f;
  for (int e = tid; e < N_EDGES; e += gridDim.x * blockDim.x) {
    int s = edge_at(ei, 0, e, f);
    int d = edge_at(ei, 1, e, f);
    const uint4* rs = fx16 + s * 4;   // 64 B row = 4 x uint4
    const uint4* rd = fx16 + d * 4;
    uint4 a0 = rs[0], a1 = rs[1], a2 = rs[2], a3 = rs[3];
    uint4 b0 = rd[0], b1 = rd[1], b2 = rd[2], b3 = rd[3];
    float acc;
    acc  = dotw(a0.x, b0.x) + dotw(a0.y, b0.y) + dotw(a0.z, b0.z) + dotw(a0.w, b0.w);
    acc += dotw(a1.x, b1.x) + dotw(a1.y, b1.y) + dotw(a1.z, b1.z) + dotw(a1.w, b1.w);
    acc += dotw(a2.x, b2.x) + dotw(a2.y, b2.y) + dotw(a2.z, b2.z) + dotw(a2.w, b2.w);
    acc += dotw(a3.x, b3.x) + dotw(a3.y, b3.y) + dotw(a3.z, b3.z) + dotw(a3.w, b3.w);
    float diff = acc - ep[e];
    local += diff * diff;
  }
  __shared__ float sd[256];
  sd[threadIdx.x] = local; __syncthreads();
  for (int off = 128; off > 0; off >>= 1) {
    if (threadIdx.x < off) sd[threadIdx.x] += sd[threadIdx.x + off];
    __syncthreads();
  }
  if (threadIdx.x == 0) atomicAdd(msed, (double)sd[0]);
}

// ---- column sums of log(1-FX^2) ----
__global__ void __launch_bounds__(256) k_colsumf(const float* FX, float* colsum) {
  __shared__ float sd[256];
  int tid = threadIdx.x;
  int j = tid & 31, g = tid >> 5;
  float local = 0.0f;
  if (j < NCLUS) {
    for (int n = blockIdx.x * 8 + g; n < N_NODES; n += gridDim.x * 8) {
      float v = FX[n * NCLUS + j];
      local += log1pf(-v * v);
    }
  }
  sd[tid] = local; __syncthreads();
  if (tid < 32) {
    float s = 0.0f;
    #pragma unroll
    for (int gg = 0; gg < 8; gg++) s += sd[tid + 32 * gg];
    if (tid < NCLUS) atomicAdd(&colsum[tid], s);
  }
}

// ---- final loss ----
__global__ void k_final(const float* colsum, const double* msed, float* out) {
  int tid = threadIdx.x;
  float v = 0.0f;
  if (tid < NCLUS) v = logf(1.0001f - __expf(colsum[tid]));
  #pragma unroll
  for (int mask = 32; mask > 0; mask >>= 1) v += __shfl_xor(v, mask, 64);
  if (tid == 0) {
    float preg = -v;
    float msev = (float)(*msed / (double)N_EDGES);
    out[(size_t)N_NODES * NCLUS] = msev + 0.01f * preg;
  }
}

extern "C" void kernel_launch(void* const* d_in, const int* in_sizes, int n_in,
                              void* d_out, int out_size, void* d_ws, size_t ws_size,
                              hipStream_t stream) {
  const float* x  = (const float*)d_in[0];
  const int*   ei = (const int*)d_in[1];
  const float* ep = (const float*)d_in[2];
  const float* W1 = (const float*)d_in[3];
  const float* b1 = (const float*)d_in[4];
  const float* W2 = (const float*)d_in[5];
  const float* b2 = (const float*)d_in[6];
  float* out = (float*)d_out;   // fp32: FX[100000*30] then loss scalar

  char* ws = (char*)d_ws;
  size_t off = 0;
  auto alloc = [&](size_t bytes) { size_t o = off; off += (bytes + 255) & ~(size_t)255; return o; };

  size_t o_hdr  = alloc(1024);                       // flag@0, msed@8(double), colsum@256, bsum@512
  size_t o_cnt  = alloc((size_t)N_NODES * 4);
  size_t o_dinv = alloc((size_t)N_NODES * 4);
  size_t o_B1   = alloc((size_t)N_NODES * 32 * 4);   // CSR: G1b/G2b (bf16) ; fallback: fp32 G
  size_t o_B2   = alloc((size_t)N_NODES * 32 * 4);   // CSR: rank -> h fp32 -> fx16 ; fallback: fp32 D

  int*    flag   = (int*)(ws + o_hdr);
  double* msed   = (double*)(ws + o_hdr + 8);
  float*  colsum = (float*)(ws + o_hdr + 256);
  int*    bsum   = (int*)(ws + o_hdr + 512);
  int*    cnt    = (int*)(ws + o_cnt);
  float*  dinv   = (float*)(ws + o_dinv);
  float*  B1f    = (float*)(ws + o_B1);
  float*  B2f    = (float*)(ws + o_B2);
  __hip_bfloat16* B1b = (__hip_bfloat16*)(ws + o_B1);
  __hip_bfloat16* B2b = (__hip_bfloat16*)(ws + o_B2);

  const int nodeBlocks = (N_NODES + 255) / 256;
  const int edgeBlocks = (N_EDGES + 255) / 256;
  const int grpBlocks  = (N_NODES + 7) / 8;
  const int elemBlocks = (N_NODES * 32 + 255) / 256;

  k_detect<<<1, 64, 0, stream>>>((const unsigned int*)ei, flag);

  size_t o_cursor = alloc((size_t)N_NODES * 4);
  size_t o_csr    = alloc((size_t)N_EDGES * 4);
  bool use_csr = (off <= ws_size);   // confirmed running since R7 (ws >= 40.3 MB)

  const __hip_bfloat16* fx16;

  if (use_csr) {
    int* cursor = (int*)(ws + o_cursor);
    int* csr    = (int*)(ws + o_csr);
    int* rank   = (int*)(ws + o_B2);   // dead until agg1b writes h

    k_zero<<<nodeBlocks, 256, 0, stream>>>(cnt, colsum, msed);
    k_countrank<<<edgeBlocks, 256, 0, stream>>>(ei, flag, cnt, rank);
    k_dinv<<<nodeBlocks, 256, 0, stream>>>(cnt, dinv);
    k_scan1<<<SCAN_NBLK, 256, 0, stream>>>(cnt, bsum);
    k_scan2<<<1, 64, 0, stream>>>(bsum);
    k_scan3<<<SCAN_NBLK, 256, 0, stream>>>(cnt, bsum, cursor);
    k_scatter2<<<edgeBlocks, 256, 0, stream>>>(ei, flag, cursor, rank, csr);

    __hip_bfloat16* G1b  = B1b;
    float*          h    = B2f;        // overwrites rank (dead after scatter2)
    __hip_bfloat16* G2b  = B1b;
    __hip_bfloat16* fx   = B2b;

    k_gemm1b<<<grpBlocks, 256, 0, stream>>>(x, W1, dinv, G1b);
    k_agg1b<<<grpBlocks, 256, 0, stream>>>(G1b, cursor, cnt, csr, dinv, b1, h);
    k_gemm2b<<<grpBlocks, 256, 0, stream>>>(h, W2, dinv, G2b);
    k_agg2b<<<grpBlocks, 256, 0, stream>>>(G2b, cursor, cnt, csr, dinv, b2, out, fx);
    fx16 = fx;
  } else {
    k_zero<<<nodeBlocks, 256, 0, stream>>>(cnt, colsum, msed);
    k_count<<<edgeBlocks, 256, 0, stream>>>(ei, flag, cnt);
    k_dinv<<<nodeBlocks, 256, 0, stream>>>(cnt, dinv);
    k_gemm1s<<<grpBlocks, 256, 0, stream>>>(x, W1, dinv, B1f);
    hipMemsetAsync(B2f, 0, (size_t)N_NODES * 32 * 4, stream);
    k_eagg2<<<8192, 256, 0, stream>>>(ei, flag, B1f, B2f);
    k_relu2<<<elemBlocks, 256, 0, stream>>>(B2f, dinv, b1, B1f);
    k_gemm2s<<<grpBlocks, 256, 0, stream>>>(B1f, W2, dinv, B2f);
    hipMemsetAsync(B1f, 0, (size_t)N_NODES * 32 * 4, stream);
    k_eagg2<<<8192, 256, 0, stream>>>(ei, flag, B2f, B1f);
    k_softmax2<<<nodeBlocks, 256, 0, stream>>>(B1f, B2f, dinv, b2, out);
    k_fx16<<<elemBlocks, 256, 0, stream>>>(out, B1b);
    fx16 = B1b;
  }

  // loss
  k_msef2<<<4096, 256, 0, stream>>>(ei, ep, (const uint4*)fx16, flag, msed);
  k_colsumf<<<256, 256, 0, stream>>>(out, colsum);
  k_final<<<1, 64, 0, stream>>>(colsum, msed, out);
}